// Round 2
// baseline (1001.664 us; speedup 1.0000x reference)
//
#include <hip/hip_runtime.h>

// MoE: T=8192 tokens, D=1024, F=4096, E=8, top-2.
// Pipeline: cast x -> transpose/cast weights to bf16 -> gate -> scatter ->
// grouped GEMM1 (x@w1+b1, gelu) -> H -> grouped GEMM2 (H@w2+b2, *gate_wt,
// atomicAdd into out).
// R3: pipelined K-loop (double LDS buffer, raw s_barrier, fine vmcnt,
// lgkmcnt(0) before the read-done barrier).
// R4: 512 thr / 8 waves of 64x32 (occupancy attack — turned out neutral).
// R5: panel-traffic attack. R4 counters: MfmaUtil 22 / VALU 10 / occ 52 /
// HBM 30% — nothing saturated => L3-path bound on A/B panel refills.
//   (a) BM=BN=256 tiles (panel bytes/FLOP halved: 15.6 -> 7.8 B/KFLOP),
//       waves 2Mx4N of 128x64 each, acc[8][4], 64KB LDS, 1 block/CU.
//   (b) bijective XCD-chunked blockIdx swizzle (grid%8==0) so the n-blocks
//       sharing an A-panel + consecutive tiles sharing B-panels co-reside
//       on one XCD's L2.
// R6: identical resubmit — R5 bench died to an infra flake ("container
// failed twice", no compile/verify signal); audit found no hang vector.

#define T_TOK 8192
#define D_DIM 1024
#define F_DIM 4096
#define E_NUM 8
#define BM 256
#define BN 256
#define BK 32
#define NK1 (D_DIM / BK)            // 32
#define NK2 (F_DIM / BK)            // 128
#define NX1 (F_DIM / BN)            // 16 n-blocks (gemm1)
#define NX2 (D_DIM / BN)            // 4 n-blocks (gemm2)
#define MAX_TILES (T_TOK * 2 / BM + E_NUM)  // 72 worst case

typedef float f32x4 __attribute__((ext_vector_type(4)));
typedef short bf16x8 __attribute__((ext_vector_type(8)));

__device__ __forceinline__ unsigned short f2bf(float f) {
  union { float f; unsigned u; } v; v.f = f;
  unsigned r = v.u + 0x7FFFu + ((v.u >> 16) & 1u);  // RNE
  return (unsigned short)(r >> 16);
}

__device__ __forceinline__ void async_cp16(const unsigned short* g, unsigned short* l) {
  // 16B-wide global->LDS DMA. LDS dest is wave-uniform base + lane*16.
  __builtin_amdgcn_global_load_lds((__attribute__((address_space(1))) void*)g,
                                   (__attribute__((address_space(3))) void*)l,
                                   16, 0, 0);
}

#define WAIT_VM4 asm volatile("s_waitcnt vmcnt(4)" ::: "memory")
#define WAIT_LGKM0 asm volatile("s_waitcnt lgkmcnt(0)" ::: "memory")
#define RAW_BARRIER asm volatile("s_barrier" ::: "memory")

// ---------------- small prep kernels ----------------

__global__ void cast_x_kernel(const float* __restrict__ src,
                              unsigned short* __restrict__ dst, int n4) {
  int i = blockIdx.x * blockDim.x + threadIdx.x;
  if (i >= n4) return;
  float4 v = ((const float4*)src)[i];
  ushort4 o;
  o.x = f2bf(v.x); o.y = f2bf(v.y); o.z = f2bf(v.z); o.w = f2bf(v.w);
  ((ushort4*)dst)[i] = o;
}

// src fp32 [R][C] row-major (per expert) -> dst bf16 [C][R].
__global__ __launch_bounds__(256) void transpose_cast_kernel(
    const float* __restrict__ src, unsigned short* __restrict__ dst,
    int R, int C) {
  __shared__ float tile[64][65];
  int e = blockIdx.z;
  src += (size_t)e * R * C;
  dst += (size_t)e * R * C;
  int c0 = blockIdx.x * 64;
  int r0 = blockIdx.y * 64;
  int t = threadIdx.x;
  int cl = (t & 15) * 4, rl = t >> 4;
#pragma unroll
  for (int i = 0; i < 4; ++i) {
    int r = rl + i * 16;
    float4 v = *(const float4*)(src + (size_t)(r0 + r) * C + c0 + cl);
    tile[r][cl + 0] = v.x;
    tile[r][cl + 1] = v.y;
    tile[r][cl + 2] = v.z;
    tile[r][cl + 3] = v.w;
  }
  __syncthreads();
  int rl2 = (t & 15) * 4, cl2 = t >> 4;
#pragma unroll
  for (int i = 0; i < 4; ++i) {
    int c = cl2 + i * 16;
    ushort4 o;
    o.x = f2bf(tile[rl2 + 0][c]);
    o.y = f2bf(tile[rl2 + 1][c]);
    o.z = f2bf(tile[rl2 + 2][c]);
    o.w = f2bf(tile[rl2 + 3][c]);
    *(ushort4*)(dst + (size_t)(c0 + c) * R + r0 + rl2) = o;
  }
}

// one wave per token: logits = x[t] . gate_w[:,e], fp32; top-2 + softmax
__global__ __launch_bounds__(256) void gate_kernel(
    const float* __restrict__ x, const float* __restrict__ gw,
    float* __restrict__ topk_w, int* __restrict__ topk_e) {
  int t = (blockIdx.x * 256 + threadIdx.x) >> 6;
  int lane = threadIdx.x & 63;
  const float* xr = x + (size_t)t * D_DIM;
  float acc[8];
#pragma unroll
  for (int e = 0; e < 8; ++e) acc[e] = 0.f;
  for (int j = 0; j < D_DIM / 64; ++j) {
    int d = lane + 64 * j;
    float xv = xr[d];
    float4 g0 = ((const float4*)(gw + (size_t)d * 8))[0];
    float4 g1 = ((const float4*)(gw + (size_t)d * 8))[1];
    acc[0] += xv * g0.x; acc[1] += xv * g0.y;
    acc[2] += xv * g0.z; acc[3] += xv * g0.w;
    acc[4] += xv * g1.x; acc[5] += xv * g1.y;
    acc[6] += xv * g1.z; acc[7] += xv * g1.w;
  }
#pragma unroll
  for (int off = 32; off > 0; off >>= 1) {
#pragma unroll
    for (int e = 0; e < 8; ++e) acc[e] += __shfl_xor(acc[e], off);
  }
  if (lane == 0) {
    int e0 = 0; float v0 = acc[0];
#pragma unroll
    for (int e = 1; e < 8; ++e)
      if (acc[e] > v0) { v0 = acc[e]; e0 = e; }  // strict >: lowest index on tie
    int e1 = -1; float v1 = -1e30f;
#pragma unroll
    for (int e = 0; e < 8; ++e)
      if (e != e0 && acc[e] > v1) { v1 = acc[e]; e1 = e; }
    float ex = expf(v1 - v0);
    float inv = 1.f / (1.f + ex);
    topk_w[2 * t] = inv;
    topk_w[2 * t + 1] = ex * inv;
    topk_e[2 * t] = e0;
    topk_e[2 * t + 1] = e1;
  }
}

__global__ void scatter_kernel(const int* __restrict__ topk_e,
                               int* __restrict__ cnt, int* __restrict__ assign) {
  int idx = blockIdx.x * blockDim.x + threadIdx.x;  // (t,k) pair id = t*2+k
  int e = topk_e[idx];
  int pos = atomicAdd(&cnt[e], 1);
  assign[e * T_TOK + pos] = idx;
}

__global__ void tiles_kernel(const int* __restrict__ cnt,
                             int* __restrict__ ndesc, int4* __restrict__ desc) {
  if (threadIdx.x != 0) return;
  int nt = 0, hb = 0;
  for (int e = 0; e < E_NUM; ++e) {
    int c = cnt[e];
    for (int s = 0; s < c; s += BM) {
      int4 d;
      d.x = e; d.y = s; d.z = hb;
      d.w = (c - s < BM) ? (c - s) : BM;
      desc[nt++] = d;
    }
    hb += c;
  }
  *ndesc = nt;
}

// ---------------- grouped GEMMs (pipelined, 256x256, 8-wave) ----------------
// 256x256 block tile, BK=32, 512 threads = 8 waves (2M x 4N) of 128x64
// (acc[8][4] = 128 AGPR, ~216 unified regs -> 2 waves/SIMD, 1 block/CU).
// Per K-step each thread issues 2 A-chunks + 2 B-chunks (chunk L and L+512);
// vmcnt(4) waits on the consumed tile, next tile's 4 stay in flight.
// LDS chunk swizzle (rotate 16B chunk by row) keeps b128 frag reads
// bank-uniform; lds-DMA forbids padding. Step:
//   vmcnt(4) ; barrier ; ds_read frags ; lgkmcnt(0) ; barrier ; issue k+2 ; MFMA
// XCD swizzle: lin = by*NX+bx (dispatch order, x fastest); wg =
// (lin%8)*(nwg/8) + lin/8 (bijective, nwg%8==0); tile = wg/NX, n = wg%NX.

// GEMM1: H[slot][f] = gelu(x[tok] @ w1[e] + b1[e]);  A gathered via assign.
__global__ __launch_bounds__(512, 2) void gemm1_kernel(
    const unsigned short* __restrict__ xb, const unsigned short* __restrict__ w1t,
    const float* __restrict__ b1, const int* __restrict__ assign,
    const int* __restrict__ ndesc, const int4* __restrict__ desc,
    unsigned short* __restrict__ H) {
  const int nwg = NX1 * MAX_TILES;                    // 1152, %8 == 0
  int lin = blockIdx.y * NX1 + blockIdx.x;
  int wg = (lin & 7) * (nwg >> 3) + (lin >> 3);
  int tileid = wg / NX1;
  int n0 = (wg & (NX1 - 1)) * BN;                     // f-offset
  if (tileid >= *ndesc) return;
  int4 dc = desc[tileid];
  int e = dc.x, start = dc.y, hbase = dc.z, mcnt = dc.w;

  __shared__ __attribute__((aligned(16))) unsigned short As[2][BM * BK];
  __shared__ __attribute__((aligned(16))) unsigned short Bs[2][BN * BK];

  int tid = threadIdx.x, lane = tid & 63, wv = tid >> 6;

  // chunk ids L = tid and tid+512 (1024 16B chunks per 16KB tile matrix)
  int row = tid >> 2, cc = tid & 3;
  int g = (cc - row) & 3;            // swizzle: LDS[row][cc] = glob[row][(cc-row)&3]
  int r1 = row + 128;                // (r1-row)%4==0 -> same g
  int r0c = row < mcnt ? row : (mcnt - 1);
  int r1c = r1 < mcnt ? r1 : (mcnt - 1);
  int a0 = assign[e * T_TOK + start + r0c];
  int a1 = assign[e * T_TOK + start + r1c];
  const unsigned short* gA0 = xb + (size_t)(a0 >> 1) * D_DIM + g * 8;
  const unsigned short* gA1 = xb + (size_t)(a1 >> 1) * D_DIM + g * 8;
  const unsigned short* gB0 = w1t + (size_t)(e * F_DIM + n0 + row) * D_DIM + g * 8;
  const unsigned short* gB1 = w1t + (size_t)(e * F_DIM + n0 + r1) * D_DIM + g * 8;
  int loff = wv * 512;               // wave-uniform LDS chunk base (shorts)

  int kc16 = lane >> 4, r16 = lane & 15;
  int m_off = (wv & 1) * 128, n_off = (wv >> 1) * 64;
  int aoff[8], boff[4];
#pragma unroll
  for (int i = 0; i < 8; ++i) {
    int ra = m_off + i * 16 + r16;
    aoff[i] = ra * 32 + ((kc16 + ra) & 3) * 8;
  }
#pragma unroll
  for (int j = 0; j < 4; ++j) {
    int rb = n_off + j * 16 + r16;
    boff[j] = rb * 32 + ((kc16 + rb) & 3) * 8;
  }

  f32x4 acc[8][4];
#pragma unroll
  for (int i = 0; i < 8; ++i)
#pragma unroll
    for (int j = 0; j < 4; ++j) acc[i][j] = (f32x4){0.f, 0.f, 0.f, 0.f};

  auto issue = [&](int t, int b) {
    int kc = (t < NK1 ? t : NK1 - 1) * BK;
    async_cp16(gA0 + kc, &As[b][loff]);
    async_cp16(gA1 + kc, &As[b][loff + 4096]);
    async_cp16(gB0 + kc, &Bs[b][loff]);
    async_cp16(gB1 + kc, &Bs[b][loff + 4096]);
  };
  auto step = [&](int kt, int b) {
    WAIT_VM4;       // tile kt's 4 DMAs done; tile kt+1's stay in flight
    RAW_BARRIER;    // all waves have tile kt in LDS
    bf16x8 af[8], bfr[4];
#pragma unroll
    for (int i = 0; i < 8; ++i) af[i] = *(const bf16x8*)(&As[b][0] + aoff[i]);
#pragma unroll
    for (int j = 0; j < 4; ++j) bfr[j] = *(const bf16x8*)(&Bs[b][0] + boff[j]);
    WAIT_LGKM0;     // DS queue drained: frags in registers
    RAW_BARRIER;    // all waves done reading buffer b -> safe to overwrite
    issue(kt + 2, b);
#pragma unroll
    for (int i = 0; i < 8; ++i)
#pragma unroll
      for (int j = 0; j < 4; ++j)
        acc[i][j] = __builtin_amdgcn_mfma_f32_16x16x32_bf16(af[i], bfr[j], acc[i][j], 0, 0, 0);
  };

  issue(0, 0);
  issue(1, 1);
  for (int kt = 0; kt < NK1; kt += 2) { step(kt, 0); step(kt + 1, 1); }

  // epilogue: C/D layout col=lane&15, row=(lane>>4)*4+reg
  int col = lane & 15, rbase = (lane >> 4) * 4;
  float bias[4];
#pragma unroll
  for (int j = 0; j < 4; ++j) bias[j] = b1[e * F_DIM + n0 + n_off + j * 16 + col];
#pragma unroll
  for (int i = 0; i < 8; ++i) {
#pragma unroll
    for (int rg = 0; rg < 4; ++rg) {
      int r = m_off + i * 16 + rbase + rg;
      if (r < mcnt) {
        unsigned short* hrow = H + (size_t)(hbase + start + r) * F_DIM + n0 + n_off + col;
#pragma unroll
        for (int j = 0; j < 4; ++j) {
          float v = acc[i][j][rg] + bias[j];
          v = 0.5f * v * (1.0f + erff(v * 0.70710678118654752f));  // exact gelu
          hrow[j * 16] = f2bf(v);
        }
      }
    }
  }
}

// GEMM2: out[tok] += wt * (H[slot] @ w2[e] + b2[e])
__global__ __launch_bounds__(512, 2) void gemm2_kernel(
    const unsigned short* __restrict__ H, const unsigned short* __restrict__ w2t,
    const float* __restrict__ b2, const int* __restrict__ assign,
    const float* __restrict__ topk_w,
    const int* __restrict__ ndesc, const int4* __restrict__ desc,
    float* __restrict__ out) {
  const int nwg = NX2 * MAX_TILES;                    // 288, %8 == 0
  int lin = blockIdx.y * NX2 + blockIdx.x;
  int wg = (lin & 7) * (nwg >> 3) + (lin >> 3);
  int tileid = wg / NX2;
  int n0 = (wg & (NX2 - 1)) * BN;                     // d-offset
  if (tileid >= *ndesc) return;
  int4 dc = desc[tileid];
  int e = dc.x, start = dc.y, hbase = dc.z, mcnt = dc.w;

  __shared__ __attribute__((aligned(16))) unsigned short As[2][BM * BK];
  __shared__ __attribute__((aligned(16))) unsigned short Bs[2][BN * BK];

  int tid = threadIdx.x, lane = tid & 63, wv = tid >> 6;

  int row = tid >> 2, cc = tid & 3;
  int g = (cc - row) & 3;
  int r1 = row + 128;
  int r0c = row < mcnt ? row : (mcnt - 1);
  int r1c = r1 < mcnt ? r1 : (mcnt - 1);
  const unsigned short* gA0 = H + (size_t)(hbase + start + r0c) * F_DIM + g * 8;
  const unsigned short* gA1 = H + (size_t)(hbase + start + r1c) * F_DIM + g * 8;
  const unsigned short* gB0 = w2t + (size_t)(e * D_DIM + n0 + row) * F_DIM + g * 8;
  const unsigned short* gB1 = w2t + (size_t)(e * D_DIM + n0 + r1) * F_DIM + g * 8;
  int loff = wv * 512;

  int kc16 = lane >> 4, r16 = lane & 15;
  int m_off = (wv & 1) * 128, n_off = (wv >> 1) * 64;
  int aoff[8], boff[4];
#pragma unroll
  for (int i = 0; i < 8; ++i) {
    int ra = m_off + i * 16 + r16;
    aoff[i] = ra * 32 + ((kc16 + ra) & 3) * 8;
  }
#pragma unroll
  for (int j = 0; j < 4; ++j) {
    int rb = n_off + j * 16 + r16;
    boff[j] = rb * 32 + ((kc16 + rb) & 3) * 8;
  }

  f32x4 acc[8][4];
#pragma unroll
  for (int i = 0; i < 8; ++i)
#pragma unroll
    for (int j = 0; j < 4; ++j) acc[i][j] = (f32x4){0.f, 0.f, 0.f, 0.f};

  auto issue = [&](int t, int b) {
    int kc = (t < NK2 ? t : NK2 - 1) * BK;
    async_cp16(gA0 + kc, &As[b][loff]);
    async_cp16(gA1 + kc, &As[b][loff + 4096]);
    async_cp16(gB0 + kc, &Bs[b][loff]);
    async_cp16(gB1 + kc, &Bs[b][loff + 4096]);
  };
  auto step = [&](int kt, int b) {
    WAIT_VM4;
    RAW_BARRIER;
    bf16x8 af[8], bfr[4];
#pragma unroll
    for (int i = 0; i < 8; ++i) af[i] = *(const bf16x8*)(&As[b][0] + aoff[i]);
#pragma unroll
    for (int j = 0; j < 4; ++j) bfr[j] = *(const bf16x8*)(&Bs[b][0] + boff[j]);
    WAIT_LGKM0;
    RAW_BARRIER;
    issue(kt + 2, b);
#pragma unroll
    for (int i = 0; i < 8; ++i)
#pragma unroll
      for (int j = 0; j < 4; ++j)
        acc[i][j] = __builtin_amdgcn_mfma_f32_16x16x32_bf16(af[i], bfr[j], acc[i][j], 0, 0, 0);
  };

  issue(0, 0);
  issue(1, 1);
  for (int kt = 0; kt < NK2; kt += 2) { step(kt, 0); step(kt + 1, 1); }

  int col = lane & 15, rbase = (lane >> 4) * 4;
  float bias[4];
#pragma unroll
  for (int j = 0; j < 4; ++j) bias[j] = b2[e * D_DIM + n0 + n_off + j * 16 + col];
#pragma unroll
  for (int i = 0; i < 8; ++i) {
#pragma unroll
    for (int rg = 0; rg < 4; ++rg) {
      int r = m_off + i * 16 + rbase + rg;
      if (r < mcnt) {
        int a = assign[e * T_TOK + start + r];
        float wt = topk_w[a];
        float* orow = out + (size_t)(a >> 1) * D_DIM + n0 + n_off + col;
#pragma unroll
        for (int j = 0; j < 4; ++j) {
          float v = acc[i][j][rg] + bias[j];
          atomicAdd(orow + j * 16, wt * v);  // 2 contenders/address
        }
      }
    }
  }
}

// ---------------- launcher ----------------

extern "C" void kernel_launch(void* const* d_in, const int* in_sizes, int n_in,
                              void* d_out, int out_size, void* d_ws, size_t ws_size,
                              hipStream_t stream) {
  const float* x      = (const float*)d_in[0];
  const float* gate_w = (const float*)d_in[1];
  const float* w1     = (const float*)d_in[2];
  const float* b1     = (const float*)d_in[3];
  const float* w2     = (const float*)d_in[4];
  const float* b2     = (const float*)d_in[5];
  float* out = (float*)d_out;

  char* ws = (char*)d_ws;
  size_t off = 0;
  auto alloc = [&](size_t bytes) {
    char* p = ws + off;
    off = (off + bytes + 255) & ~(size_t)255;
    return p;
  };
  unsigned short* xb   = (unsigned short*)alloc((size_t)T_TOK * D_DIM * 2);
  unsigned short* w1t  = (unsigned short*)alloc((size_t)E_NUM * D_DIM * F_DIM * 2);
  unsigned short* w2t  = (unsigned short*)alloc((size_t)E_NUM * D_DIM * F_DIM * 2);
  unsigned short* Hbuf = (unsigned short*)alloc((size_t)2 * T_TOK * F_DIM * 2);
  float* topk_w = (float*)alloc((size_t)2 * T_TOK * 4);
  int* topk_e   = (int*)alloc((size_t)2 * T_TOK * 4);
  int* assign   = (int*)alloc((size_t)E_NUM * T_TOK * 4);
  int* cnt      = (int*)alloc(64);
  int* ndesc    = (int*)alloc(64);
  int4* desc    = (int4*)alloc((size_t)MAX_TILES * 16);

  hipMemsetAsync(cnt, 0, 64, stream);
  hipMemsetAsync(out, 0, (size_t)out_size * 4, stream);

  cast_x_kernel<<<(T_TOK * D_DIM / 4 + 255) / 256, 256, 0, stream>>>(
      x, xb, T_TOK * D_DIM / 4);
  transpose_cast_kernel<<<dim3(F_DIM / 64, D_DIM / 64, E_NUM), 256, 0, stream>>>(
      w1, w1t, D_DIM, F_DIM);  // [D][F] -> [F][D]
  transpose_cast_kernel<<<dim3(D_DIM / 64, F_DIM / 64, E_NUM), 256, 0, stream>>>(
      w2, w2t, F_DIM, D_DIM);  // [F][D] -> [D][F]
  gate_kernel<<<T_TOK / 4, 256, 0, stream>>>(x, gate_w, topk_w, topk_e);
  scatter_kernel<<<2 * T_TOK / 256, 256, 0, stream>>>(topk_e, cnt, assign);
  tiles_kernel<<<1, 64, 0, stream>>>(cnt, ndesc, desc);
  gemm1_kernel<<<dim3(NX1, MAX_TILES), 512, 0, stream>>>(
      xb, w1t, b1, assign, ndesc, desc, Hbuf);
  gemm2_kernel<<<dim3(NX2, MAX_TILES), 512, 0, stream>>>(
      Hbuf, w2t, b2, assign, topk_w, ndesc, desc, out);
}

// Round 3
// 935.063 us; speedup vs baseline: 1.0712x; 1.0712x over previous
//
#include <hip/hip_runtime.h>

// MoE: T=8192 tokens, D=1024, F=4096, E=8, top-2.
// Pipeline: cast x -> transpose/cast weights to bf16 -> gate -> scatter ->
// grouped GEMM1 (x@w1+b1, gelu) -> H -> grouped GEMM2 (H@w2+b2, *gate_wt,
// atomicAdd into out).
// R4: 128^2 2-phase, multi-block: gemm2 277us, MfmaUtil 22.
// R6: 256^2 2-phase + XCD swizzle: FETCH 597->152MB (theory confirmed) but
// dur WORSE (339us, occ 12%) -> 2-phase lockstep stall fully exposed at
// 1 block/CU. Schedule structure is the limiter, not traffic.
// R7: 8-phase counted-vmcnt schedule (T3+T4+T5) on 256^2, BK=64:
//   - 4 phases per K-tile; phase = {ds_read subtile; issue 1 slab-pair DMA;
//     barrier; lgkmcnt(0); setprio(1); 16 MFMA; setprio(0); barrier}
//   - vmcnt(6) ONCE per K-tile (last phase) — 6 loads (3 slab-pairs) stay
//     in flight across the wait; never drains to 0 in the loop.
//   - slab re-stage schedule proven race-free: B slabs re-staged from
//     phase 1 (B fully read in phase 0), A quarters 0-1 from phase 3,
//     A quarters 2-3 deferred to next tile's phase 0.
//   - 128KB dynamic LDS (2 dbuf x (32KB A + 32KB B)), chunk-rot-8 swizzle
//     (LDS[row][cc]=glob[row][(cc-row)&7]) -> b128 frag reads 2-way (free).
//   - keeps R6's bijective XCD-chunked blockIdx swizzle (FETCH win).

#define T_TOK 8192
#define D_DIM 1024
#define F_DIM 4096
#define E_NUM 8
#define BM 256
#define BN 256
#define BK 64
#define NK1 (D_DIM / BK)            // 16
#define NK2 (F_DIM / BK)            // 64
#define NX1 (F_DIM / BN)            // 16 n-blocks (gemm1)
#define NX2 (D_DIM / BN)            // 4 n-blocks (gemm2)
#define MAX_TILES (T_TOK * 2 / BM + E_NUM)  // 72 worst case

typedef float f32x4 __attribute__((ext_vector_type(4)));
typedef short bf16x8 __attribute__((ext_vector_type(8)));

__device__ __forceinline__ unsigned short f2bf(float f) {
  union { float f; unsigned u; } v; v.f = f;
  unsigned r = v.u + 0x7FFFu + ((v.u >> 16) & 1u);  // RNE
  return (unsigned short)(r >> 16);
}

__device__ __forceinline__ void async_cp16(const unsigned short* g, unsigned short* l) {
  // 16B-wide global->LDS DMA. LDS dest is wave-uniform base + lane*16.
  __builtin_amdgcn_global_load_lds((__attribute__((address_space(1))) void*)g,
                                   (__attribute__((address_space(3))) void*)l,
                                   16, 0, 0);
}

#define WAIT_VM6 asm volatile("s_waitcnt vmcnt(6)" ::: "memory")
#define WAIT_LGKM0 asm volatile("s_waitcnt lgkmcnt(0)" ::: "memory")
#define RAW_BARRIER asm volatile("s_barrier" ::: "memory")

// ---------------- small prep kernels ----------------

__global__ void cast_x_kernel(const float* __restrict__ src,
                              unsigned short* __restrict__ dst, int n4) {
  int i = blockIdx.x * blockDim.x + threadIdx.x;
  if (i >= n4) return;
  float4 v = ((const float4*)src)[i];
  ushort4 o;
  o.x = f2bf(v.x); o.y = f2bf(v.y); o.z = f2bf(v.z); o.w = f2bf(v.w);
  ((ushort4*)dst)[i] = o;
}

// src fp32 [R][C] row-major (per expert) -> dst bf16 [C][R].
__global__ __launch_bounds__(256) void transpose_cast_kernel(
    const float* __restrict__ src, unsigned short* __restrict__ dst,
    int R, int C) {
  __shared__ float tile[64][65];
  int e = blockIdx.z;
  src += (size_t)e * R * C;
  dst += (size_t)e * R * C;
  int c0 = blockIdx.x * 64;
  int r0 = blockIdx.y * 64;
  int t = threadIdx.x;
  int cl = (t & 15) * 4, rl = t >> 4;
#pragma unroll
  for (int i = 0; i < 4; ++i) {
    int r = rl + i * 16;
    float4 v = *(const float4*)(src + (size_t)(r0 + r) * C + c0 + cl);
    tile[r][cl + 0] = v.x;
    tile[r][cl + 1] = v.y;
    tile[r][cl + 2] = v.z;
    tile[r][cl + 3] = v.w;
  }
  __syncthreads();
  int rl2 = (t & 15) * 4, cl2 = t >> 4;
#pragma unroll
  for (int i = 0; i < 4; ++i) {
    int c = cl2 + i * 16;
    ushort4 o;
    o.x = f2bf(tile[rl2 + 0][c]);
    o.y = f2bf(tile[rl2 + 1][c]);
    o.z = f2bf(tile[rl2 + 2][c]);
    o.w = f2bf(tile[rl2 + 3][c]);
    *(ushort4*)(dst + (size_t)(c0 + c) * R + r0 + rl2) = o;
  }
}

// one wave per token: logits = x[t] . gate_w[:,e], fp32; top-2 + softmax
__global__ __launch_bounds__(256) void gate_kernel(
    const float* __restrict__ x, const float* __restrict__ gw,
    float* __restrict__ topk_w, int* __restrict__ topk_e) {
  int t = (blockIdx.x * 256 + threadIdx.x) >> 6;
  int lane = threadIdx.x & 63;
  const float* xr = x + (size_t)t * D_DIM;
  float acc[8];
#pragma unroll
  for (int e = 0; e < 8; ++e) acc[e] = 0.f;
  for (int j = 0; j < D_DIM / 64; ++j) {
    int d = lane + 64 * j;
    float xv = xr[d];
    float4 g0 = ((const float4*)(gw + (size_t)d * 8))[0];
    float4 g1 = ((const float4*)(gw + (size_t)d * 8))[1];
    acc[0] += xv * g0.x; acc[1] += xv * g0.y;
    acc[2] += xv * g0.z; acc[3] += xv * g0.w;
    acc[4] += xv * g1.x; acc[5] += xv * g1.y;
    acc[6] += xv * g1.z; acc[7] += xv * g1.w;
  }
#pragma unroll
  for (int off = 32; off > 0; off >>= 1) {
#pragma unroll
    for (int e = 0; e < 8; ++e) acc[e] += __shfl_xor(acc[e], off);
  }
  if (lane == 0) {
    int e0 = 0; float v0 = acc[0];
#pragma unroll
    for (int e = 1; e < 8; ++e)
      if (acc[e] > v0) { v0 = acc[e]; e0 = e; }  // strict >: lowest index on tie
    int e1 = -1; float v1 = -1e30f;
#pragma unroll
    for (int e = 0; e < 8; ++e)
      if (e != e0 && acc[e] > v1) { v1 = acc[e]; e1 = e; }
    float ex = expf(v1 - v0);
    float inv = 1.f / (1.f + ex);
    topk_w[2 * t] = inv;
    topk_w[2 * t + 1] = ex * inv;
    topk_e[2 * t] = e0;
    topk_e[2 * t + 1] = e1;
  }
}

__global__ void scatter_kernel(const int* __restrict__ topk_e,
                               int* __restrict__ cnt, int* __restrict__ assign) {
  int idx = blockIdx.x * blockDim.x + threadIdx.x;  // (t,k) pair id = t*2+k
  int e = topk_e[idx];
  int pos = atomicAdd(&cnt[e], 1);
  assign[e * T_TOK + pos] = idx;
}

__global__ void tiles_kernel(const int* __restrict__ cnt,
                             int* __restrict__ ndesc, int4* __restrict__ desc) {
  if (threadIdx.x != 0) return;
  int nt = 0, hb = 0;
  for (int e = 0; e < E_NUM; ++e) {
    int c = cnt[e];
    for (int s = 0; s < c; s += BM) {
      int4 d;
      d.x = e; d.y = s; d.z = hb;
      d.w = (c - s < BM) ? (c - s) : BM;
      desc[nt++] = d;
    }
    hb += c;
  }
  *ndesc = nt;
}

// ---------------- grouped GEMMs (8-phase, 256x256, BK=64) ----------------
// 512 threads = 8 waves (2M x 4N), per-wave output 128x64, acc[8][4].
// LDS (dynamic, 128KB): [A0 32KB][B0 32KB][A1 32KB][B1 32KB]; tile matrix =
// 256 rows x 64 bf16; DMA call j (4 per matrix per K-tile) = 64-row slab
// (chunk L = tid + 512j, row = L>>3, cc = L&7, pre-swizzled source chunk
// g = (cc-row)&7 -> b128 frag reads are 2-way bank (free).
// Per K-tile t (buf p = t&1), 4 phases; phase q computes M-frags {2q,2q+1}
// x 4 N-frags x K64 = 16 MFMA. B-frags (8 b128) read once in phase 0.
// Issue schedule (2 DMA per phase, all into correct buffer by parity):
//   q0: A(t+1) slabs 1,3 (rows 64-127/192-255 of buf p^1 - consumed thru
//       prev tile's q3, safe after its closing barrier)
//   q1: B(t+2) slabs 0,1   (B of buf p fully read in q0)
//   q2: B(t+2) slabs 2,3
//   q3: A(t+2) slabs 0,2   (rows 0-63/128-191 = q0/q1 rows, done by q2)
// vmcnt(6) at end of q3 -> all of T(t+1) landed, T(t+2)'s 6 still flying.
// Clamped issues past NK re-stage the last tile's bytes (identical data,
// benign). In-loop VMEM ops are ONLY these DMAs, so vmcnt counts exactly.

// GEMM1: H[slot][f] = gelu(x[tok] @ w1[e] + b1[e]);  A gathered via assign.
__global__ __launch_bounds__(512, 2) void gemm1_kernel(
    const unsigned short* __restrict__ xb, const unsigned short* __restrict__ w1t,
    const float* __restrict__ b1, const int* __restrict__ assign,
    const int* __restrict__ ndesc, const int4* __restrict__ desc,
    unsigned short* __restrict__ H) {
  const int nwg = NX1 * MAX_TILES;                    // 1152, %8 == 0
  int lin = blockIdx.y * NX1 + blockIdx.x;
  int wg = (lin & 7) * (nwg >> 3) + (lin >> 3);
  int tileid = wg / NX1;
  int n0 = (wg & (NX1 - 1)) * BN;                     // f-offset
  if (tileid >= *ndesc) return;
  int4 dc = desc[tileid];
  int e = dc.x, start = dc.y, hbase = dc.z, mcnt = dc.w;

  extern __shared__ __attribute__((aligned(16))) unsigned short smem[];

  int tid = threadIdx.x, lane = tid & 63, wv = tid >> 6;

  int drow = tid >> 3, dcc = tid & 7;
  int g = (dcc - drow) & 7;          // pre-swizzled source chunk
  const unsigned short* gAr[4];
  const unsigned short* gBr[4];
#pragma unroll
  for (int j = 0; j < 4; ++j) {
    int r = drow + 64 * j;
    int rc = r < mcnt ? r : (mcnt - 1);
    int a = assign[e * T_TOK + start + rc];
    gAr[j] = xb + (size_t)(a >> 1) * D_DIM + g * 8;
    gBr[j] = w1t + (size_t)(e * F_DIM + n0 + r) * D_DIM + g * 8;
  }
  int ldst = wv * 512;               // wave LDS chunk base (shorts); +j*4096/call

  int kc16 = lane >> 4, r16 = lane & 15;
  int m_off = (wv & 1) * 128, n_off = (wv >> 1) * 64;

  f32x4 acc[8][4];
#pragma unroll
  for (int i = 0; i < 8; ++i)
#pragma unroll
    for (int j = 0; j < 4; ++j) acc[i][j] = (f32x4){0.f, 0.f, 0.f, 0.f};
  bf16x8 bfr[4][2];

  auto issueA = [&](int t, int j) {
    int kt = t < NK1 ? t : NK1 - 1;
    async_cp16(gAr[j] + kt * 64, smem + (t & 1) * 32768 + ldst + j * 4096);
  };
  auto issueB = [&](int t, int j) {
    int kt = t < NK1 ? t : NK1 - 1;
    async_cp16(gBr[j] + kt * 64, smem + (t & 1) * 32768 + 16384 + ldst + j * 4096);
  };

  auto phase = [&](int t, int q) {
    const unsigned short* Ab = smem + (t & 1) * 32768;
    const unsigned short* Bb = Ab + 16384;
    if (q == 0) {
#pragma unroll
      for (int j = 0; j < 4; ++j) {
        int rb = n_off + j * 16 + r16;
#pragma unroll
        for (int h = 0; h < 2; ++h)
          bfr[j][h] = *(const bf16x8*)(Bb + rb * 64 + ((h * 4 + kc16 + rb) & 7) * 8);
      }
    }
    bf16x8 af[2][2];
#pragma unroll
    for (int m2 = 0; m2 < 2; ++m2) {
      int ra = m_off + (2 * q + m2) * 16 + r16;
#pragma unroll
      for (int h = 0; h < 2; ++h)
        af[m2][h] = *(const bf16x8*)(Ab + ra * 64 + ((h * 4 + kc16 + ra) & 7) * 8);
    }
    if (q == 0)      { issueA(t + 1, 1); issueA(t + 1, 3); }
    else if (q == 1) { issueB(t + 2, 0); issueB(t + 2, 1); }
    else if (q == 2) { issueB(t + 2, 2); issueB(t + 2, 3); }
    else             { issueA(t + 2, 0); issueA(t + 2, 2); }
    RAW_BARRIER;
    WAIT_LGKM0;
    __builtin_amdgcn_s_setprio(1);
#pragma unroll
    for (int h = 0; h < 2; ++h)
#pragma unroll
      for (int m2 = 0; m2 < 2; ++m2)
#pragma unroll
        for (int j = 0; j < 4; ++j)
          acc[2 * q + m2][j] = __builtin_amdgcn_mfma_f32_16x16x32_bf16(
              af[m2][h], bfr[j][h], acc[2 * q + m2][j], 0, 0, 0);
    __builtin_amdgcn_s_setprio(0);
    if (q == 3) WAIT_VM6;
    RAW_BARRIER;
  };

  // prologue: T0 all 8 calls, then T1's first 6; vmcnt(6) -> T0 landed.
#pragma unroll
  for (int j = 0; j < 4; ++j) issueB(0, j);
#pragma unroll
  for (int j = 0; j < 4; ++j) issueA(0, j);
  issueB(1, 0); issueB(1, 1); issueB(1, 2); issueB(1, 3);
  issueA(1, 0); issueA(1, 2);
  WAIT_VM6;
  RAW_BARRIER;

  for (int t = 0; t < NK1; ++t) {
    phase(t, 0); phase(t, 1); phase(t, 2); phase(t, 3);
  }

  // epilogue: C/D layout col=lane&15, row=(lane>>4)*4+reg
  int col = lane & 15, rbase = (lane >> 4) * 4;
  float bias[4];
#pragma unroll
  for (int j = 0; j < 4; ++j) bias[j] = b1[e * F_DIM + n0 + n_off + j * 16 + col];
#pragma unroll
  for (int i = 0; i < 8; ++i) {
#pragma unroll
    for (int rg = 0; rg < 4; ++rg) {
      int r = m_off + i * 16 + rbase + rg;
      if (r < mcnt) {
        unsigned short* hrow = H + (size_t)(hbase + start + r) * F_DIM + n0 + n_off + col;
#pragma unroll
        for (int j = 0; j < 4; ++j) {
          float v = acc[i][j][rg] + bias[j];
          v = 0.5f * v * (1.0f + erff(v * 0.70710678118654752f));  // exact gelu
          hrow[j * 16] = f2bf(v);
        }
      }
    }
  }
}

// GEMM2: out[tok] += wt * (H[slot] @ w2[e] + b2[e])
__global__ __launch_bounds__(512, 2) void gemm2_kernel(
    const unsigned short* __restrict__ H, const unsigned short* __restrict__ w2t,
    const float* __restrict__ b2, const int* __restrict__ assign,
    const float* __restrict__ topk_w,
    const int* __restrict__ ndesc, const int4* __restrict__ desc,
    float* __restrict__ out) {
  const int nwg = NX2 * MAX_TILES;                    // 288, %8 == 0
  int lin = blockIdx.y * NX2 + blockIdx.x;
  int wg = (lin & 7) * (nwg >> 3) + (lin >> 3);
  int tileid = wg / NX2;
  int n0 = (wg & (NX2 - 1)) * BN;                     // d-offset
  if (tileid >= *ndesc) return;
  int4 dc = desc[tileid];
  int e = dc.x, start = dc.y, hbase = dc.z, mcnt = dc.w;

  extern __shared__ __attribute__((aligned(16))) unsigned short smem[];

  int tid = threadIdx.x, lane = tid & 63, wv = tid >> 6;

  int drow = tid >> 3, dcc = tid & 7;
  int g = (dcc - drow) & 7;
  const unsigned short* gAr[4];
  const unsigned short* gBr[4];
#pragma unroll
  for (int j = 0; j < 4; ++j) {
    int r = drow + 64 * j;
    int rc = r < mcnt ? r : (mcnt - 1);
    gAr[j] = H + (size_t)(hbase + start + rc) * F_DIM + g * 8;
    gBr[j] = w2t + (size_t)(e * D_DIM + n0 + r) * F_DIM + g * 8;
  }
  int ldst = wv * 512;

  int kc16 = lane >> 4, r16 = lane & 15;
  int m_off = (wv & 1) * 128, n_off = (wv >> 1) * 64;

  f32x4 acc[8][4];
#pragma unroll
  for (int i = 0; i < 8; ++i)
#pragma unroll
    for (int j = 0; j < 4; ++j) acc[i][j] = (f32x4){0.f, 0.f, 0.f, 0.f};
  bf16x8 bfr[4][2];

  auto issueA = [&](int t, int j) {
    int kt = t < NK2 ? t : NK2 - 1;
    async_cp16(gAr[j] + kt * 64, smem + (t & 1) * 32768 + ldst + j * 4096);
  };
  auto issueB = [&](int t, int j) {
    int kt = t < NK2 ? t : NK2 - 1;
    async_cp16(gBr[j] + kt * 64, smem + (t & 1) * 32768 + 16384 + ldst + j * 4096);
  };

  auto phase = [&](int t, int q) {
    const unsigned short* Ab = smem + (t & 1) * 32768;
    const unsigned short* Bb = Ab + 16384;
    if (q == 0) {
#pragma unroll
      for (int j = 0; j < 4; ++j) {
        int rb = n_off + j * 16 + r16;
#pragma unroll
        for (int h = 0; h < 2; ++h)
          bfr[j][h] = *(const bf16x8*)(Bb + rb * 64 + ((h * 4 + kc16 + rb) & 7) * 8);
      }
    }
    bf16x8 af[2][2];
#pragma unroll
    for (int m2 = 0; m2 < 2; ++m2) {
      int ra = m_off + (2 * q + m2) * 16 + r16;
#pragma unroll
      for (int h = 0; h < 2; ++h)
        af[m2][h] = *(const bf16x8*)(Ab + ra * 64 + ((h * 4 + kc16 + ra) & 7) * 8);
    }
    if (q == 0)      { issueA(t + 1, 1); issueA(t + 1, 3); }
    else if (q == 1) { issueB(t + 2, 0); issueB(t + 2, 1); }
    else if (q == 2) { issueB(t + 2, 2); issueB(t + 2, 3); }
    else             { issueA(t + 2, 0); issueA(t + 2, 2); }
    RAW_BARRIER;
    WAIT_LGKM0;
    __builtin_amdgcn_s_setprio(1);
#pragma unroll
    for (int h = 0; h < 2; ++h)
#pragma unroll
      for (int m2 = 0; m2 < 2; ++m2)
#pragma unroll
        for (int j = 0; j < 4; ++j)
          acc[2 * q + m2][j] = __builtin_amdgcn_mfma_f32_16x16x32_bf16(
              af[m2][h], bfr[j][h], acc[2 * q + m2][j], 0, 0, 0);
    __builtin_amdgcn_s_setprio(0);
    if (q == 3) WAIT_VM6;
    RAW_BARRIER;
  };

#pragma unroll
  for (int j = 0; j < 4; ++j) issueB(0, j);
#pragma unroll
  for (int j = 0; j < 4; ++j) issueA(0, j);
  issueB(1, 0); issueB(1, 1); issueB(1, 2); issueB(1, 3);
  issueA(1, 0); issueA(1, 2);
  WAIT_VM6;
  RAW_BARRIER;

  for (int t = 0; t < NK2; ++t) {
    phase(t, 0); phase(t, 1); phase(t, 2); phase(t, 3);
  }

  int col = lane & 15, rbase = (lane >> 4) * 4;
  float bias[4];
#pragma unroll
  for (int j = 0; j < 4; ++j) bias[j] = b2[e * D_DIM + n0 + n_off + j * 16 + col];
#pragma unroll
  for (int i = 0; i < 8; ++i) {
#pragma unroll
    for (int rg = 0; rg < 4; ++rg) {
      int r = m_off + i * 16 + rbase + rg;
      if (r < mcnt) {
        int a = assign[e * T_TOK + start + r];
        float wt = topk_w[a];
        float* orow = out + (size_t)(a >> 1) * D_DIM + n0 + n_off + col;
#pragma unroll
        for (int j = 0; j < 4; ++j) {
          float v = acc[i][j][rg] + bias[j];
          atomicAdd(orow + j * 16, wt * v);  // 2 contenders/address
        }
      }
    }
  }
}

// ---------------- launcher ----------------

extern "C" void kernel_launch(void* const* d_in, const int* in_sizes, int n_in,
                              void* d_out, int out_size, void* d_ws, size_t ws_size,
                              hipStream_t stream) {
  const float* x      = (const float*)d_in[0];
  const float* gate_w = (const float*)d_in[1];
  const float* w1     = (const float*)d_in[2];
  const float* b1     = (const float*)d_in[3];
  const float* w2     = (const float*)d_in[4];
  const float* b2     = (const float*)d_in[5];
  float* out = (float*)d_out;

  char* ws = (char*)d_ws;
  size_t off = 0;
  auto alloc = [&](size_t bytes) {
    char* p = ws + off;
    off = (off + bytes + 255) & ~(size_t)255;
    return p;
  };
  unsigned short* xb   = (unsigned short*)alloc((size_t)T_TOK * D_DIM * 2);
  unsigned short* w1t  = (unsigned short*)alloc((size_t)E_NUM * D_DIM * F_DIM * 2);
  unsigned short* w2t  = (unsigned short*)alloc((size_t)E_NUM * D_DIM * F_DIM * 2);
  unsigned short* Hbuf = (unsigned short*)alloc((size_t)2 * T_TOK * F_DIM * 2);
  float* topk_w = (float*)alloc((size_t)2 * T_TOK * 4);
  int* topk_e   = (int*)alloc((size_t)2 * T_TOK * 4);
  int* assign   = (int*)alloc((size_t)E_NUM * T_TOK * 4);
  int* cnt      = (int*)alloc(64);
  int* ndesc    = (int*)alloc(64);
  int4* desc    = (int4*)alloc((size_t)MAX_TILES * 16);

  // raise dynamic-LDS cap to 128KB for the GEMMs (host-side, capture-safe)
  hipFuncSetAttribute(reinterpret_cast<const void*>(gemm1_kernel),
                      hipFuncAttributeMaxDynamicSharedMemorySize, 131072);
  hipFuncSetAttribute(reinterpret_cast<const void*>(gemm2_kernel),
                      hipFuncAttributeMaxDynamicSharedMemorySize, 131072);

  hipMemsetAsync(cnt, 0, 64, stream);
  hipMemsetAsync(out, 0, (size_t)out_size * 4, stream);

  cast_x_kernel<<<(T_TOK * D_DIM / 4 + 255) / 256, 256, 0, stream>>>(
      x, xb, T_TOK * D_DIM / 4);
  transpose_cast_kernel<<<dim3(F_DIM / 64, D_DIM / 64, E_NUM), 256, 0, stream>>>(
      w1, w1t, D_DIM, F_DIM);  // [D][F] -> [F][D]
  transpose_cast_kernel<<<dim3(D_DIM / 64, F_DIM / 64, E_NUM), 256, 0, stream>>>(
      w2, w2t, F_DIM, D_DIM);  // [F][D] -> [D][F]
  gate_kernel<<<T_TOK / 4, 256, 0, stream>>>(x, gate_w, topk_w, topk_e);
  scatter_kernel<<<2 * T_TOK / 256, 256, 0, stream>>>(topk_e, cnt, assign);
  tiles_kernel<<<1, 64, 0, stream>>>(cnt, ndesc, desc);
  gemm1_kernel<<<dim3(NX1, MAX_TILES), 512, 131072, stream>>>(
      xb, w1t, b1, assign, ndesc, desc, Hbuf);
  gemm2_kernel<<<dim3(NX2, MAX_TILES), 512, 131072, stream>>>(
      Hbuf, w2t, b2, assign, topk_w, ndesc, desc, out);
}

// Round 4
// 860.897 us; speedup vs baseline: 1.1635x; 1.0862x over previous
//
#include <hip/hip_runtime.h>

// MoE: T=8192 tokens, D=1024, F=4096, E=8, top-2.
// R6: 256^2+XCD swizzle: FETCH 597->152MB but 2-phase lockstep exposed.
// R7: 8-phase counted-vmcnt: gemm2 287us, MfmaUtil 21, bank-conflict 0.
//     Cycle audit: per K-tile MFMA=2484 cyc vs 5360 measured; the gap is
//     LDS-read time (~580cyc/phase) SERIALIZED with MFMA by the 2
//     barriers/phase, plus gemm2's 272-blocks-on-256-CUs tail (53% util).
// R8: (a) ONE barrier per phase: lgkmcnt(0) moved before the end-barrier,
//     mid-barrier deleted. Safe: every DMA targets a region whose reads
//     drained before a PRIOR closing barrier (gap schedule re-verified).
//     Cross-wave LDS/MFMA overlap now possible.
//     (b) gemm2 re-tiled BM=128 x BN=256 (desc2, ~528 blocks -> 69% packing
//     vs 53%), 2 phases/tile, 96KB LDS, vmcnt(4) once/tile, A slabs aligned
//     to per-phase consumption rows.
//     (c) prep: cast fused into gate; ballot-aggregated scatter (8x fewer
//     atomics); 16B transpose stores.

#define T_TOK 8192
#define D_DIM 1024
#define F_DIM 4096
#define E_NUM 8
#define BM 256
#define BN 256
#define BK 64
#define NK1 (D_DIM / BK)            // 16
#define NK2 (F_DIM / BK)            // 64
#define NX1 (F_DIM / BN)            // 16 n-blocks (gemm1)
#define NX2 (D_DIM / BN)            // 4 n-blocks (gemm2)
#define MAX_TILES (T_TOK * 2 / BM + E_NUM)    // 72 (gemm1, BM=256)
#define BM2 128
#define MAX_TILES2 (T_TOK * 2 / BM2 + E_NUM)  // 136 (gemm2, BM=128)

typedef float f32x4 __attribute__((ext_vector_type(4)));
typedef short bf16x8 __attribute__((ext_vector_type(8)));
typedef unsigned short u16x8 __attribute__((ext_vector_type(8)));

__device__ __forceinline__ unsigned short f2bf(float f) {
  union { float f; unsigned u; } v; v.f = f;
  unsigned r = v.u + 0x7FFFu + ((v.u >> 16) & 1u);  // RNE
  return (unsigned short)(r >> 16);
}

__device__ __forceinline__ void async_cp16(const unsigned short* g, unsigned short* l) {
  // 16B-wide global->LDS DMA. LDS dest is wave-uniform base + lane*16.
  __builtin_amdgcn_global_load_lds((__attribute__((address_space(1))) void*)g,
                                   (__attribute__((address_space(3))) void*)l,
                                   16, 0, 0);
}

#define WAIT_VM6 asm volatile("s_waitcnt vmcnt(6)" ::: "memory")
#define WAIT_VM4 asm volatile("s_waitcnt vmcnt(4)" ::: "memory")
#define WAIT_LGKM0 asm volatile("s_waitcnt lgkmcnt(0)" ::: "memory")
#define RAW_BARRIER asm volatile("s_barrier" ::: "memory")

// ---------------- small prep kernels ----------------

// src fp32 [R][C] row-major (per expert) -> dst bf16 [C][R].
__global__ __launch_bounds__(256) void transpose_cast_kernel(
    const float* __restrict__ src, unsigned short* __restrict__ dst,
    int R, int C) {
  __shared__ float tile[64][65];
  int e = blockIdx.z;
  src += (size_t)e * R * C;
  dst += (size_t)e * R * C;
  int c0 = blockIdx.x * 64;
  int r0 = blockIdx.y * 64;
  int t = threadIdx.x;
  int cl = (t & 15) * 4, rl = t >> 4;
#pragma unroll
  for (int i = 0; i < 4; ++i) {
    int r = rl + i * 16;
    float4 v = *(const float4*)(src + (size_t)(r0 + r) * C + c0 + cl);
    tile[r][cl + 0] = v.x;
    tile[r][cl + 1] = v.y;
    tile[r][cl + 2] = v.z;
    tile[r][cl + 3] = v.w;
  }
  __syncthreads();
  int rl2 = (t & 7) * 8, cl2 = t >> 3;   // 16B stores: 8 rows per thread
#pragma unroll
  for (int i = 0; i < 2; ++i) {
    int c = cl2 + i * 32;
    u16x8 o;
#pragma unroll
    for (int k = 0; k < 8; ++k) o[k] = f2bf(tile[rl2 + k][c]);
    *(u16x8*)(dst + (size_t)(c0 + c) * R + r0 + rl2) = o;
  }
}

// one wave per token: logits = x[t].gate_w[:,e]; top-2 + softmax.
// Fused: also emits the bf16 cast of x (saves the separate cast pass).
__global__ __launch_bounds__(256) void gate_kernel(
    const float* __restrict__ x, const float* __restrict__ gw,
    float* __restrict__ topk_w, int* __restrict__ topk_e,
    unsigned short* __restrict__ xb) {
  int t = (blockIdx.x * 256 + threadIdx.x) >> 6;
  int lane = threadIdx.x & 63;
  const float* xr = x + (size_t)t * D_DIM;
  unsigned short* xbr = xb + (size_t)t * D_DIM;
  float acc[8];
#pragma unroll
  for (int e = 0; e < 8; ++e) acc[e] = 0.f;
  for (int j = 0; j < D_DIM / 64; ++j) {
    int d = lane + 64 * j;
    float xv = xr[d];
    xbr[d] = f2bf(xv);
    float4 g0 = ((const float4*)(gw + (size_t)d * 8))[0];
    float4 g1 = ((const float4*)(gw + (size_t)d * 8))[1];
    acc[0] += xv * g0.x; acc[1] += xv * g0.y;
    acc[2] += xv * g0.z; acc[3] += xv * g0.w;
    acc[4] += xv * g1.x; acc[5] += xv * g1.y;
    acc[6] += xv * g1.z; acc[7] += xv * g1.w;
  }
#pragma unroll
  for (int off = 32; off > 0; off >>= 1) {
#pragma unroll
    for (int e = 0; e < 8; ++e) acc[e] += __shfl_xor(acc[e], off);
  }
  if (lane == 0) {
    int e0 = 0; float v0 = acc[0];
#pragma unroll
    for (int e = 1; e < 8; ++e)
      if (acc[e] > v0) { v0 = acc[e]; e0 = e; }  // strict >: lowest index on tie
    int e1 = -1; float v1 = -1e30f;
#pragma unroll
    for (int e = 0; e < 8; ++e)
      if (e != e0 && acc[e] > v1) { v1 = acc[e]; e1 = e; }
    float ex = expf(v1 - v0);
    float inv = 1.f / (1.f + ex);
    topk_w[2 * t] = inv;
    topk_w[2 * t + 1] = ex * inv;
    topk_e[2 * t] = e0;
    topk_e[2 * t + 1] = e1;
  }
}

// ballot-aggregated: one atomic per (wave, expert) instead of per thread.
__global__ void scatter_kernel(const int* __restrict__ topk_e,
                               int* __restrict__ cnt, int* __restrict__ assign) {
  int idx = blockIdx.x * blockDim.x + threadIdx.x;  // (t,k) pair id = t*2+k
  int e = topk_e[idx];
  int lane = threadIdx.x & 63;
#pragma unroll
  for (int ex = 0; ex < E_NUM; ++ex) {
    unsigned long long m = __ballot(e == ex);
    if (e == ex) {
      int src = __ffsll((unsigned long long)m) - 1;
      int nbefore = __popcll(m & ((1ull << lane) - 1ull));
      int base = 0;
      if (lane == src) base = atomicAdd(&cnt[ex], __popcll(m));
      base = __shfl(base, src);
      assign[ex * T_TOK + base + nbefore] = idx;
    }
  }
}

__global__ void tiles_kernel(const int* __restrict__ cnt,
                             int* __restrict__ ndesc, int4* __restrict__ desc,
                             int4* __restrict__ desc2) {
  if (threadIdx.x != 0) return;
  int nt = 0, nt2 = 0, hb = 0;
  for (int e = 0; e < E_NUM; ++e) {
    int c = cnt[e];
    for (int s = 0; s < c; s += BM) {
      int4 d;
      d.x = e; d.y = s; d.z = hb;
      d.w = (c - s < BM) ? (c - s) : BM;
      desc[nt++] = d;
    }
    for (int s = 0; s < c; s += BM2) {
      int4 d;
      d.x = e; d.y = s; d.z = hb;
      d.w = (c - s < BM2) ? (c - s) : BM2;
      desc2[nt2++] = d;
    }
    hb += c;
  }
  ndesc[0] = nt;
  ndesc[1] = nt2;
}

// ---------------- GEMM1 (8 waves, 256x256, BK=64, 4 phases/tile) ----------
// Phase: {ds_read frags; issue DMA pair; lgkmcnt(0); MFMA x16; [q3:vmcnt(6)];
// s_barrier}. ONE barrier/phase: all reads drain (lgkm0) before the closing
// barrier, and every DMA targets a region drained before a PRIOR barrier:
//   q0: A(t+1) slabs 1,3 (rows 64-127/192-255: consumed q2/q3 of t-1)
//   q1: B(t+2) slabs 0,1 (B consumed q0 of t)
//   q2: B(t+2) slabs 2,3
//   q3: A(t+2) slabs 0,2 (rows 0-63/128-191: consumed q0/q1 of t)
// vmcnt(6) at q3: tile t+1 fully landed per wave, t+2's 6 stay in flight.

__global__ __launch_bounds__(512, 2) void gemm1_kernel(
    const unsigned short* __restrict__ xb, const unsigned short* __restrict__ w1t,
    const float* __restrict__ b1, const int* __restrict__ assign,
    const int* __restrict__ ndesc, const int4* __restrict__ desc,
    unsigned short* __restrict__ H) {
  const int nwg = NX1 * MAX_TILES;                    // 1152, %8 == 0
  int lin = blockIdx.y * NX1 + blockIdx.x;
  int wg = (lin & 7) * (nwg >> 3) + (lin >> 3);
  int tileid = wg / NX1;
  int n0 = (wg & (NX1 - 1)) * BN;                     // f-offset
  if (tileid >= ndesc[0]) return;
  int4 dc = desc[tileid];
  int e = dc.x, start = dc.y, hbase = dc.z, mcnt = dc.w;

  extern __shared__ __attribute__((aligned(16))) unsigned short smem[];

  int tid = threadIdx.x, lane = tid & 63, wv = tid >> 6;

  int drow = tid >> 3, dcc = tid & 7;
  int g = (dcc - drow) & 7;          // pre-swizzled source chunk
  const unsigned short* gAr[4];
  const unsigned short* gBr[4];
#pragma unroll
  for (int j = 0; j < 4; ++j) {
    int r = drow + 64 * j;
    int rc = r < mcnt ? r : (mcnt - 1);
    int a = assign[e * T_TOK + start + rc];
    gAr[j] = xb + (size_t)(a >> 1) * D_DIM + g * 8;
    gBr[j] = w1t + (size_t)(e * F_DIM + n0 + r) * D_DIM + g * 8;
  }
  int ldst = wv * 512;               // wave LDS chunk base (shorts)

  int kc16 = lane >> 4, r16 = lane & 15;
  int m_off = (wv & 1) * 128, n_off = (wv >> 1) * 64;

  f32x4 acc[8][4];
#pragma unroll
  for (int i = 0; i < 8; ++i)
#pragma unroll
    for (int j = 0; j < 4; ++j) acc[i][j] = (f32x4){0.f, 0.f, 0.f, 0.f};
  bf16x8 bfr[4][2];

  auto issueA = [&](int t, int j) {
    int kt = t < NK1 ? t : NK1 - 1;
    async_cp16(gAr[j] + kt * 64, smem + (t & 1) * 32768 + ldst + j * 4096);
  };
  auto issueB = [&](int t, int j) {
    int kt = t < NK1 ? t : NK1 - 1;
    async_cp16(gBr[j] + kt * 64, smem + (t & 1) * 32768 + 16384 + ldst + j * 4096);
  };

  auto phase = [&](int t, int q) {
    const unsigned short* Ab = smem + (t & 1) * 32768;
    const unsigned short* Bb = Ab + 16384;
    if (q == 0) {
#pragma unroll
      for (int j = 0; j < 4; ++j) {
        int rb = n_off + j * 16 + r16;
#pragma unroll
        for (int h = 0; h < 2; ++h)
          bfr[j][h] = *(const bf16x8*)(Bb + rb * 64 + ((h * 4 + kc16 + rb) & 7) * 8);
      }
    }
    bf16x8 af[2][2];
#pragma unroll
    for (int m2 = 0; m2 < 2; ++m2) {
      int ra = m_off + (2 * q + m2) * 16 + r16;
#pragma unroll
      for (int h = 0; h < 2; ++h)
        af[m2][h] = *(const bf16x8*)(Ab + ra * 64 + ((h * 4 + kc16 + ra) & 7) * 8);
    }
    if (q == 0)      { issueA(t + 1, 1); issueA(t + 1, 3); }
    else if (q == 1) { issueB(t + 2, 0); issueB(t + 2, 1); }
    else if (q == 2) { issueB(t + 2, 2); issueB(t + 2, 3); }
    else             { issueA(t + 2, 0); issueA(t + 2, 2); }
    WAIT_LGKM0;     // own reads drained before the closing barrier
    __builtin_amdgcn_s_setprio(1);
#pragma unroll
    for (int h = 0; h < 2; ++h)
#pragma unroll
      for (int m2 = 0; m2 < 2; ++m2)
#pragma unroll
        for (int j = 0; j < 4; ++j)
          acc[2 * q + m2][j] = __builtin_amdgcn_mfma_f32_16x16x32_bf16(
              af[m2][h], bfr[j][h], acc[2 * q + m2][j], 0, 0, 0);
    __builtin_amdgcn_s_setprio(0);
    if (q == 3) WAIT_VM6;
    RAW_BARRIER;
  };

  // prologue: T0 all 8 calls, then T1's first 6; vmcnt(6) -> T0 landed.
#pragma unroll
  for (int j = 0; j < 4; ++j) issueB(0, j);
#pragma unroll
  for (int j = 0; j < 4; ++j) issueA(0, j);
  issueB(1, 0); issueB(1, 1); issueB(1, 2); issueB(1, 3);
  issueA(1, 0); issueA(1, 2);
  WAIT_VM6;
  RAW_BARRIER;

  for (int t = 0; t < NK1; ++t) {
    phase(t, 0); phase(t, 1); phase(t, 2); phase(t, 3);
  }

  // epilogue: C/D layout col=lane&15, row=(lane>>4)*4+reg
  int col = lane & 15, rbase = (lane >> 4) * 4;
  float bias[4];
#pragma unroll
  for (int j = 0; j < 4; ++j) bias[j] = b1[e * F_DIM + n0 + n_off + j * 16 + col];
#pragma unroll
  for (int i = 0; i < 8; ++i) {
#pragma unroll
    for (int rg = 0; rg < 4; ++rg) {
      int r = m_off + i * 16 + rbase + rg;
      if (r < mcnt) {
        unsigned short* hrow = H + (size_t)(hbase + start + r) * F_DIM + n0 + n_off + col;
#pragma unroll
        for (int j = 0; j < 4; ++j) {
          float v = acc[i][j][rg] + bias[j];
          v = 0.5f * v * (1.0f + erff(v * 0.70710678118654752f));  // exact gelu
          hrow[j * 16] = f2bf(v);
        }
      }
    }
  }
}

// ---------------- GEMM2 (8 waves, 128x256, BK=64, 2 phases/tile) ----------
// 528-ish blocks -> 2.06 dispatch rounds (69% packing vs 53% at BM=256).
// LDS 96KB: buf p at p*24576 shorts: [A 128x64 = 8192][B 256x64 = 16384].
// A slabs aligned to phase consumption: slab j covers rows
// (drow&31)+(drow>>5)*64 + j*32  (slab0 = q0 rows {0-31,64-95}, slab1 = q1
// rows {32-63,96-127}); B slabs j*64 plain (all consumed in q0).
//   q0: reads B(8)+A m01(4); issue {B(t+1,3), A(t+1,1)}; MFMA m01.
//   q1: reads A m23(4); issue {B(t+2,0..2), A(t+2,0)}; MFMA m23; vmcnt(4).
// vmcnt(4) leaves q1's own 4 in flight; q0's 2 (tail of t+1) landed.

__global__ __launch_bounds__(512, 2) void gemm2_kernel(
    const unsigned short* __restrict__ H, const unsigned short* __restrict__ w2t,
    const float* __restrict__ b2, const int* __restrict__ assign,
    const float* __restrict__ topk_w,
    const int* __restrict__ ndesc, const int4* __restrict__ desc2,
    float* __restrict__ out) {
  const int nwg = NX2 * MAX_TILES2;                   // 544, %8 == 0
  int lin = blockIdx.y * NX2 + blockIdx.x;
  int wg = (lin & 7) * (nwg >> 3) + (lin >> 3);
  int tileid = wg / NX2;
  int n0 = (wg & (NX2 - 1)) * BN;                     // d-offset
  if (tileid >= ndesc[1]) return;
  int4 dc = desc2[tileid];
  int e = dc.x, start = dc.y, hbase = dc.z, mcnt = dc.w;

  extern __shared__ __attribute__((aligned(16))) unsigned short smem[];

  int tid = threadIdx.x, lane = tid & 63, wv = tid >> 6;

  int drow = tid >> 3, dcc = tid & 7;
  int g = (dcc - drow) & 7;
  const unsigned short* gA2[2];
  const unsigned short* gB2[4];
#pragma unroll
  for (int j = 0; j < 2; ++j) {
    int r = (drow & 31) + (drow >> 5) * 64 + j * 32;  // phase-aligned slab rows
    int rc = r < mcnt ? r : (mcnt - 1);
    gA2[j] = H + (size_t)(hbase + start + rc) * F_DIM + g * 8;
  }
#pragma unroll
  for (int j = 0; j < 4; ++j) {
    int r = drow + j * 64;
    gB2[j] = w2t + (size_t)(e * D_DIM + n0 + r) * F_DIM + g * 8;
  }
  int arowbase = ((wv * 8) & 31) + ((wv * 8) >> 5) * 64;  // wave-uniform
  int ldstB = wv * 512;

  int kc16 = lane >> 4, r16 = lane & 15;
  int m_off = (wv & 1) * 64, n_off = (wv >> 1) * 64;

  f32x4 acc[4][4];
#pragma unroll
  for (int i = 0; i < 4; ++i)
#pragma unroll
    for (int j = 0; j < 4; ++j) acc[i][j] = (f32x4){0.f, 0.f, 0.f, 0.f};
  bf16x8 bfr[4][2];

  auto issueA = [&](int t, int j) {
    int kt = t < NK2 ? t : NK2 - 1;
    async_cp16(gA2[j] + kt * 64,
               smem + (t & 1) * 24576 + (arowbase + j * 32) * 64);
  };
  auto issueB = [&](int t, int j) {
    int kt = t < NK2 ? t : NK2 - 1;
    async_cp16(gB2[j] + kt * 64,
               smem + (t & 1) * 24576 + 8192 + ldstB + j * 4096);
  };

  auto phase = [&](int t, int q) {
    const unsigned short* Ab = smem + (t & 1) * 24576;
    const unsigned short* Bb = Ab + 8192;
    if (q == 0) {
#pragma unroll
      for (int j = 0; j < 4; ++j) {
        int rb = n_off + j * 16 + r16;
#pragma unroll
        for (int h = 0; h < 2; ++h)
          bfr[j][h] = *(const bf16x8*)(Bb + rb * 64 + ((h * 4 + kc16 + rb) & 7) * 8);
      }
    }
    bf16x8 af[2][2];
#pragma unroll
    for (int m2 = 0; m2 < 2; ++m2) {
      int ra = m_off + (2 * q + m2) * 16 + r16;
#pragma unroll
      for (int h = 0; h < 2; ++h)
        af[m2][h] = *(const bf16x8*)(Ab + ra * 64 + ((h * 4 + kc16 + ra) & 7) * 8);
    }
    if (q == 0) { issueB(t + 1, 3); issueA(t + 1, 1); }
    else        { issueB(t + 2, 0); issueB(t + 2, 1); issueB(t + 2, 2); issueA(t + 2, 0); }
    WAIT_LGKM0;
    __builtin_amdgcn_s_setprio(1);
#pragma unroll
    for (int h = 0; h < 2; ++h)
#pragma unroll
      for (int m2 = 0; m2 < 2; ++m2)
#pragma unroll
        for (int j = 0; j < 4; ++j)
          acc[2 * q + m2][j] = __builtin_amdgcn_mfma_f32_16x16x32_bf16(
              af[m2][h], bfr[j][h], acc[2 * q + m2][j], 0, 0, 0);
    __builtin_amdgcn_s_setprio(0);
    if (q == 1) WAIT_VM4;
    RAW_BARRIER;
  };

  // prologue: T0 all 6, T1's first 4; vmcnt(4) -> T0 landed.
  issueB(0, 0); issueB(0, 1); issueB(0, 2); issueB(0, 3);
  issueA(0, 0); issueA(0, 1);
  issueB(1, 0); issueB(1, 1); issueB(1, 2);
  issueA(1, 0);
  WAIT_VM4;
  RAW_BARRIER;

  for (int t = 0; t < NK2; ++t) { phase(t, 0); phase(t, 1); }

  int col = lane & 15, rbase = (lane >> 4) * 4;
  float bias[4];
#pragma unroll
  for (int j = 0; j < 4; ++j) bias[j] = b2[e * D_DIM + n0 + n_off + j * 16 + col];
#pragma unroll
  for (int i = 0; i < 4; ++i) {
#pragma unroll
    for (int rg = 0; rg < 4; ++rg) {
      int r = m_off + i * 16 + rbase + rg;
      if (r < mcnt) {
        int a = assign[e * T_TOK + start + r];
        float wt = topk_w[a];
        float* orow = out + (size_t)(a >> 1) * D_DIM + n0 + n_off + col;
#pragma unroll
        for (int j = 0; j < 4; ++j) {
          float v = acc[i][j][rg] + bias[j];
          atomicAdd(orow + j * 16, wt * v);  // 2 contenders/address
        }
      }
    }
  }
}

// ---------------- launcher ----------------

extern "C" void kernel_launch(void* const* d_in, const int* in_sizes, int n_in,
                              void* d_out, int out_size, void* d_ws, size_t ws_size,
                              hipStream_t stream) {
  const float* x      = (const float*)d_in[0];
  const float* gate_w = (const float*)d_in[1];
  const float* w1     = (const float*)d_in[2];
  const float* b1     = (const float*)d_in[3];
  const float* w2     = (const float*)d_in[4];
  const float* b2     = (const float*)d_in[5];
  float* out = (float*)d_out;

  char* ws = (char*)d_ws;
  size_t off = 0;
  auto alloc = [&](size_t bytes) {
    char* p = ws + off;
    off = (off + bytes + 255) & ~(size_t)255;
    return p;
  };
  unsigned short* xb   = (unsigned short*)alloc((size_t)T_TOK * D_DIM * 2);
  unsigned short* w1t  = (unsigned short*)alloc((size_t)E_NUM * D_DIM * F_DIM * 2);
  unsigned short* w2t  = (unsigned short*)alloc((size_t)E_NUM * D_DIM * F_DIM * 2);
  unsigned short* Hbuf = (unsigned short*)alloc((size_t)2 * T_TOK * F_DIM * 2);
  float* topk_w = (float*)alloc((size_t)2 * T_TOK * 4);
  int* topk_e   = (int*)alloc((size_t)2 * T_TOK * 4);
  int* assign   = (int*)alloc((size_t)E_NUM * T_TOK * 4);
  int* cnt      = (int*)alloc(64);
  int* ndesc    = (int*)alloc(64);
  int4* desc    = (int4*)alloc((size_t)MAX_TILES * 16);
  int4* desc2   = (int4*)alloc((size_t)MAX_TILES2 * 16);

  hipFuncSetAttribute(reinterpret_cast<const void*>(gemm1_kernel),
                      hipFuncAttributeMaxDynamicSharedMemorySize, 131072);
  hipFuncSetAttribute(reinterpret_cast<const void*>(gemm2_kernel),
                      hipFuncAttributeMaxDynamicSharedMemorySize, 98304);

  hipMemsetAsync(cnt, 0, 64, stream);
  hipMemsetAsync(out, 0, (size_t)out_size * 4, stream);

  transpose_cast_kernel<<<dim3(F_DIM / 64, D_DIM / 64, E_NUM), 256, 0, stream>>>(
      w1, w1t, D_DIM, F_DIM);  // [D][F] -> [F][D]
  transpose_cast_kernel<<<dim3(D_DIM / 64, F_DIM / 64, E_NUM), 256, 0, stream>>>(
      w2, w2t, F_DIM, D_DIM);  // [F][D] -> [D][F]
  gate_kernel<<<T_TOK / 4, 256, 0, stream>>>(x, gate_w, topk_w, topk_e, xb);
  scatter_kernel<<<2 * T_TOK / 256, 256, 0, stream>>>(topk_e, cnt, assign);
  tiles_kernel<<<1, 64, 0, stream>>>(cnt, ndesc, desc, desc2);
  gemm1_kernel<<<dim3(NX1, MAX_TILES), 512, 131072, stream>>>(
      xb, w1t, b1, assign, ndesc, desc, Hbuf);
  gemm2_kernel<<<dim3(NX2, MAX_TILES2), 512, 98304, stream>>>(
      Hbuf, w2t, b2, assign, topk_w, ndesc, desc2, out);
}

// Round 6
// 845.859 us; speedup vs baseline: 1.1842x; 1.0178x over previous
//
#include <hip/hip_runtime.h>

// MoE: T=8192 tokens, D=1024, F=4096, E=8, top-2.
// R6: 256^2+XCD swizzle: FETCH 597->152MB; 2-phase lockstep exposed.
// R7: 8-phase counted-vmcnt: MfmaUtil 21. R8: 1 barrier/phase + gemm2
// 128x256 + prep fusion: 861us total, gemm1 now top (272us, Mfma 22.8,
// VALU 40.6). Cycle audit: ds_read_b128 port time (~2k cyc/tile) ~= MFMA
// time (2.5k) and 4 sync points/tile serialize them; VALU 40% = libm erff.
// R9: (a) 2 super-phases per K-tile (32 MFMA each); manual lgkm0 moved
//     AFTER the MFMA cluster (pre-barrier drain only) -> compiler emits
//     fine per-operand lgkmcnt, reads overlap MFMA within and across waves.
//     Slab invariants re-derived for 2 barriers/tile:
//       H0 issues A(t+1) slabs 1,3   (readers: t-1 H1, barrier passed)
//       H1 issues B(t+2) 0..3 + A(t+2) slabs 0,2 (readers: t H0)
//     vmcnt(6) once per tile at H1 (B(t+2)x4 + A(t+2)x2 stay in flight).
//     (b) erff -> A&S 7.1.26 poly (rcp + __expf + 5 FMA, abs err 1.5e-7).
//     (c) post-loop vmcnt(0) drain (in-flight LDS-DMA vs endpgm safety).
// R10: identical resubmit — R9 bench died to the same infra flake as R1
//     ("container failed twice", no compile/verify signal); full audit of
//     the new sync structure (vmcnt ledgers, slab-overwrite invariants,
//     barrier uniformity) found no hang vector.

#define T_TOK 8192
#define D_DIM 1024
#define F_DIM 4096
#define E_NUM 8
#define BM 256
#define BN 256
#define BK 64
#define NK1 (D_DIM / BK)            // 16
#define NK2 (F_DIM / BK)            // 64
#define NX1 (F_DIM / BN)            // 16 n-blocks (gemm1)
#define NX2 (D_DIM / BN)            // 4 n-blocks (gemm2)
#define MAX_TILES (T_TOK * 2 / BM + E_NUM)    // 72 (gemm1, BM=256)
#define BM2 128
#define MAX_TILES2 (T_TOK * 2 / BM2 + E_NUM)  // 136 (gemm2, BM=128)

typedef float f32x4 __attribute__((ext_vector_type(4)));
typedef short bf16x8 __attribute__((ext_vector_type(8)));
typedef unsigned short u16x8 __attribute__((ext_vector_type(8)));

__device__ __forceinline__ unsigned short f2bf(float f) {
  union { float f; unsigned u; } v; v.f = f;
  unsigned r = v.u + 0x7FFFu + ((v.u >> 16) & 1u);  // RNE
  return (unsigned short)(r >> 16);
}

// gelu via A&S 7.1.26 erf poly: |err(erf)| <= 1.5e-7, way below bf16 ulp.
__device__ __forceinline__ float gelu_f(float v) {
  float z = v * 0.70710678118654752f;
  float az = fabsf(z);
  float t = 1.0f / (1.0f + 0.3275911f * az);
  float p = ((((1.061405429f * t - 1.453152027f) * t + 1.421413741f) * t
              - 0.284496736f) * t + 0.254829592f) * t;
  float E = 1.0f - p * __expf(-az * az);
  float er = z < 0.f ? -E : E;
  return 0.5f * v * (1.0f + er);
}

__device__ __forceinline__ void async_cp16(const unsigned short* g, unsigned short* l) {
  // 16B-wide global->LDS DMA. LDS dest is wave-uniform base + lane*16.
  __builtin_amdgcn_global_load_lds((__attribute__((address_space(1))) void*)g,
                                   (__attribute__((address_space(3))) void*)l,
                                   16, 0, 0);
}

#define WAIT_VM6 asm volatile("s_waitcnt vmcnt(6)" ::: "memory")
#define WAIT_VM4 asm volatile("s_waitcnt vmcnt(4)" ::: "memory")
#define WAIT_VM0 asm volatile("s_waitcnt vmcnt(0)" ::: "memory")
#define WAIT_LGKM0 asm volatile("s_waitcnt lgkmcnt(0)" ::: "memory")
#define RAW_BARRIER asm volatile("s_barrier" ::: "memory")

// ---------------- small prep kernels ----------------

// src fp32 [R][C] row-major (per expert) -> dst bf16 [C][R].
__global__ __launch_bounds__(256) void transpose_cast_kernel(
    const float* __restrict__ src, unsigned short* __restrict__ dst,
    int R, int C) {
  __shared__ float tile[64][65];
  int e = blockIdx.z;
  src += (size_t)e * R * C;
  dst += (size_t)e * R * C;
  int c0 = blockIdx.x * 64;
  int r0 = blockIdx.y * 64;
  int t = threadIdx.x;
  int cl = (t & 15) * 4, rl = t >> 4;
#pragma unroll
  for (int i = 0; i < 4; ++i) {
    int r = rl + i * 16;
    float4 v = *(const float4*)(src + (size_t)(r0 + r) * C + c0 + cl);
    tile[r][cl + 0] = v.x;
    tile[r][cl + 1] = v.y;
    tile[r][cl + 2] = v.z;
    tile[r][cl + 3] = v.w;
  }
  __syncthreads();
  int rl2 = (t & 7) * 8, cl2 = t >> 3;   // 16B stores: 8 rows per thread
#pragma unroll
  for (int i = 0; i < 2; ++i) {
    int c = cl2 + i * 32;
    u16x8 o;
#pragma unroll
    for (int k = 0; k < 8; ++k) o[k] = f2bf(tile[rl2 + k][c]);
    *(u16x8*)(dst + (size_t)(c0 + c) * R + r0 + rl2) = o;
  }
}

// one wave per token: logits = x[t].gate_w[:,e]; top-2 + softmax.
// Fused: also emits the bf16 cast of x (saves the separate cast pass).
__global__ __launch_bounds__(256) void gate_kernel(
    const float* __restrict__ x, const float* __restrict__ gw,
    float* __restrict__ topk_w, int* __restrict__ topk_e,
    unsigned short* __restrict__ xb) {
  int t = (blockIdx.x * 256 + threadIdx.x) >> 6;
  int lane = threadIdx.x & 63;
  const float* xr = x + (size_t)t * D_DIM;
  unsigned short* xbr = xb + (size_t)t * D_DIM;
  float acc[8];
#pragma unroll
  for (int e = 0; e < 8; ++e) acc[e] = 0.f;
  for (int j = 0; j < D_DIM / 64; ++j) {
    int d = lane + 64 * j;
    float xv = xr[d];
    xbr[d] = f2bf(xv);
    float4 g0 = ((const float4*)(gw + (size_t)d * 8))[0];
    float4 g1 = ((const float4*)(gw + (size_t)d * 8))[1];
    acc[0] += xv * g0.x; acc[1] += xv * g0.y;
    acc[2] += xv * g0.z; acc[3] += xv * g0.w;
    acc[4] += xv * g1.x; acc[5] += xv * g1.y;
    acc[6] += xv * g1.z; acc[7] += xv * g1.w;
  }
#pragma unroll
  for (int off = 32; off > 0; off >>= 1) {
#pragma unroll
    for (int e = 0; e < 8; ++e) acc[e] += __shfl_xor(acc[e], off);
  }
  if (lane == 0) {
    int e0 = 0; float v0 = acc[0];
#pragma unroll
    for (int e = 1; e < 8; ++e)
      if (acc[e] > v0) { v0 = acc[e]; e0 = e; }  // strict >: lowest index on tie
    int e1 = -1; float v1 = -1e30f;
#pragma unroll
    for (int e = 0; e < 8; ++e)
      if (e != e0 && acc[e] > v1) { v1 = acc[e]; e1 = e; }
    float ex = expf(v1 - v0);
    float inv = 1.f / (1.f + ex);
    topk_w[2 * t] = inv;
    topk_w[2 * t + 1] = ex * inv;
    topk_e[2 * t] = e0;
    topk_e[2 * t + 1] = e1;
  }
}

// ballot-aggregated: one atomic per (wave, expert) instead of per thread.
__global__ void scatter_kernel(const int* __restrict__ topk_e,
                               int* __restrict__ cnt, int* __restrict__ assign) {
  int idx = blockIdx.x * blockDim.x + threadIdx.x;  // (t,k) pair id = t*2+k
  int e = topk_e[idx];
  int lane = threadIdx.x & 63;
#pragma unroll
  for (int ex = 0; ex < E_NUM; ++ex) {
    unsigned long long m = __ballot(e == ex);
    if (e == ex) {
      int src = __ffsll((unsigned long long)m) - 1;
      int nbefore = __popcll(m & ((1ull << lane) - 1ull));
      int base = 0;
      if (lane == src) base = atomicAdd(&cnt[ex], __popcll(m));
      base = __shfl(base, src);
      assign[ex * T_TOK + base + nbefore] = idx;
    }
  }
}

__global__ void tiles_kernel(const int* __restrict__ cnt,
                             int* __restrict__ ndesc, int4* __restrict__ desc,
                             int4* __restrict__ desc2) {
  if (threadIdx.x != 0) return;
  int nt = 0, nt2 = 0, hb = 0;
  for (int e = 0; e < E_NUM; ++e) {
    int c = cnt[e];
    for (int s = 0; s < c; s += BM) {
      int4 d;
      d.x = e; d.y = s; d.z = hb;
      d.w = (c - s < BM) ? (c - s) : BM;
      desc[nt++] = d;
    }
    for (int s = 0; s < c; s += BM2) {
      int4 d;
      d.x = e; d.y = s; d.z = hb;
      d.w = (c - s < BM2) ? (c - s) : BM2;
      desc2[nt2++] = d;
    }
    hb += c;
  }
  ndesc[0] = nt;
  ndesc[1] = nt2;
}

// ---------------- GEMM1 (8 waves, 256x256, BK=64, 2 super-phases/tile) ----
// Super-phase = {ds_read frags; issue DMAs; 32 MFMA (compiler fine-waits
// operands); [H1: vmcnt(6)]; lgkmcnt(0); s_barrier}.
// H0 reads B(8)+A m0-3(8), computes acc[0..3][*]; H1 reads A m4-7(8),
// computes acc[4..7][*]. A rows per half: H0 = m_off+0..63 (slabs 0/2),
// H1 = m_off+64..127 (slabs 1/3).

__global__ __launch_bounds__(512, 2) void gemm1_kernel(
    const unsigned short* __restrict__ xb, const unsigned short* __restrict__ w1t,
    const float* __restrict__ b1, const int* __restrict__ assign,
    const int* __restrict__ ndesc, const int4* __restrict__ desc,
    unsigned short* __restrict__ H) {
  const int nwg = NX1 * MAX_TILES;                    // 1152, %8 == 0
  int lin = blockIdx.y * NX1 + blockIdx.x;
  int wg = (lin & 7) * (nwg >> 3) + (lin >> 3);
  int tileid = wg / NX1;
  int n0 = (wg & (NX1 - 1)) * BN;                     // f-offset
  if (tileid >= ndesc[0]) return;
  int4 dc = desc[tileid];
  int e = dc.x, start = dc.y, hbase = dc.z, mcnt = dc.w;

  extern __shared__ __attribute__((aligned(16))) unsigned short smem[];

  int tid = threadIdx.x, lane = tid & 63, wv = tid >> 6;

  int drow = tid >> 3, dcc = tid & 7;
  int g = (dcc - drow) & 7;          // pre-swizzled source chunk
  const unsigned short* gAr[4];
  const unsigned short* gBr[4];
#pragma unroll
  for (int j = 0; j < 4; ++j) {
    int r = drow + 64 * j;
    int rc = r < mcnt ? r : (mcnt - 1);
    int a = assign[e * T_TOK + start + rc];
    gAr[j] = xb + (size_t)(a >> 1) * D_DIM + g * 8;
    gBr[j] = w1t + (size_t)(e * F_DIM + n0 + r) * D_DIM + g * 8;
  }
  int ldst = wv * 512;               // wave LDS chunk base (shorts)

  int kc16 = lane >> 4, r16 = lane & 15;
  int m_off = (wv & 1) * 128, n_off = (wv >> 1) * 64;

  f32x4 acc[8][4];
#pragma unroll
  for (int i = 0; i < 8; ++i)
#pragma unroll
    for (int j = 0; j < 4; ++j) acc[i][j] = (f32x4){0.f, 0.f, 0.f, 0.f};
  bf16x8 bfr[4][2];

  auto issueA = [&](int t, int j) {
    int kt = t < NK1 ? t : NK1 - 1;
    async_cp16(gAr[j] + kt * 64, smem + (t & 1) * 32768 + ldst + j * 4096);
  };
  auto issueB = [&](int t, int j) {
    int kt = t < NK1 ? t : NK1 - 1;
    async_cp16(gBr[j] + kt * 64, smem + (t & 1) * 32768 + 16384 + ldst + j * 4096);
  };

  auto half0 = [&](int t) {
    const unsigned short* Ab = smem + (t & 1) * 32768;
    const unsigned short* Bb = Ab + 16384;
#pragma unroll
    for (int j = 0; j < 4; ++j) {
      int rb = n_off + j * 16 + r16;
#pragma unroll
      for (int h = 0; h < 2; ++h)
        bfr[j][h] = *(const bf16x8*)(Bb + rb * 64 + ((h * 4 + kc16 + rb) & 7) * 8);
    }
    bf16x8 af[4][2];
#pragma unroll
    for (int m = 0; m < 4; ++m) {
      int ra = m_off + m * 16 + r16;
#pragma unroll
      for (int h = 0; h < 2; ++h)
        af[m][h] = *(const bf16x8*)(Ab + ra * 64 + ((h * 4 + kc16 + ra) & 7) * 8);
    }
    issueA(t + 1, 1); issueA(t + 1, 3);
    __builtin_amdgcn_s_setprio(1);
#pragma unroll
    for (int h = 0; h < 2; ++h)
#pragma unroll
      for (int m = 0; m < 4; ++m)
#pragma unroll
        for (int j = 0; j < 4; ++j)
          acc[m][j] = __builtin_amdgcn_mfma_f32_16x16x32_bf16(
              af[m][h], bfr[j][h], acc[m][j], 0, 0, 0);
    __builtin_amdgcn_s_setprio(0);
    WAIT_LGKM0;     // pre-barrier drain (cross-wave DMA-overwrite safety)
    RAW_BARRIER;
  };
  auto half1 = [&](int t) {
    const unsigned short* Ab = smem + (t & 1) * 32768;
    bf16x8 af[4][2];
#pragma unroll
    for (int m = 0; m < 4; ++m) {
      int ra = m_off + (4 + m) * 16 + r16;
#pragma unroll
      for (int h = 0; h < 2; ++h)
        af[m][h] = *(const bf16x8*)(Ab + ra * 64 + ((h * 4 + kc16 + ra) & 7) * 8);
    }
    issueB(t + 2, 0); issueB(t + 2, 1); issueB(t + 2, 2); issueB(t + 2, 3);
    issueA(t + 2, 0); issueA(t + 2, 2);
    __builtin_amdgcn_s_setprio(1);
#pragma unroll
    for (int h = 0; h < 2; ++h)
#pragma unroll
      for (int m = 0; m < 4; ++m)
#pragma unroll
        for (int j = 0; j < 4; ++j)
          acc[4 + m][j] = __builtin_amdgcn_mfma_f32_16x16x32_bf16(
              af[m][h], bfr[j][h], acc[4 + m][j], 0, 0, 0);
    __builtin_amdgcn_s_setprio(0);
    WAIT_VM6;
    WAIT_LGKM0;
    RAW_BARRIER;
  };

  // prologue: T0 all 8 calls, then T1's first 6; vmcnt(6) -> T0 landed.
#pragma unroll
  for (int j = 0; j < 4; ++j) issueB(0, j);
#pragma unroll
  for (int j = 0; j < 4; ++j) issueA(0, j);
  issueB(1, 0); issueB(1, 1); issueB(1, 2); issueB(1, 3);
  issueA(1, 0); issueA(1, 2);
  WAIT_VM6;
  RAW_BARRIER;

  for (int t = 0; t < NK1; ++t) { half0(t); half1(t); }
  WAIT_VM0;        // drain stray DMAs before epilogue/endpgm (LDS safety)

  // epilogue: C/D layout col=lane&15, row=(lane>>4)*4+reg
  int col = lane & 15, rbase = (lane >> 4) * 4;
  float bias[4];
#pragma unroll
  for (int j = 0; j < 4; ++j) bias[j] = b1[e * F_DIM + n0 + n_off + j * 16 + col];
#pragma unroll
  for (int i = 0; i < 8; ++i) {
#pragma unroll
    for (int rg = 0; rg < 4; ++rg) {
      int r = m_off + i * 16 + rbase + rg;
      if (r < mcnt) {
        unsigned short* hrow = H + (size_t)(hbase + start + r) * F_DIM + n0 + n_off + col;
#pragma unroll
        for (int j = 0; j < 4; ++j) {
          float v = gelu_f(acc[i][j][rg] + bias[j]);
          hrow[j * 16] = f2bf(v);
        }
      }
    }
  }
}

// ---------------- GEMM2 (8 waves, 128x256, BK=64, 2 phases/tile) ----------
// Same as R8 but lgkm0 moved after the MFMA cluster (fine operand waits).
//   q0: reads B(8)+A m01(4); issue {B(t+1,3), A(t+1,1)}; MFMA m01.
//   q1: reads A m23(4); issue {B(t+2,0..2), A(t+2,0)}; MFMA m23; vmcnt(4).

__global__ __launch_bounds__(512, 2) void gemm2_kernel(
    const unsigned short* __restrict__ H, const unsigned short* __restrict__ w2t,
    const float* __restrict__ b2, const int* __restrict__ assign,
    const float* __restrict__ topk_w,
    const int* __restrict__ ndesc, const int4* __restrict__ desc2,
    float* __restrict__ out) {
  const int nwg = NX2 * MAX_TILES2;                   // 544, %8 == 0
  int lin = blockIdx.y * NX2 + blockIdx.x;
  int wg = (lin & 7) * (nwg >> 3) + (lin >> 3);
  int tileid = wg / NX2;
  int n0 = (wg & (NX2 - 1)) * BN;                     // d-offset
  if (tileid >= ndesc[1]) return;
  int4 dc = desc2[tileid];
  int e = dc.x, start = dc.y, hbase = dc.z, mcnt = dc.w;

  extern __shared__ __attribute__((aligned(16))) unsigned short smem[];

  int tid = threadIdx.x, lane = tid & 63, wv = tid >> 6;

  int drow = tid >> 3, dcc = tid & 7;
  int g = (dcc - drow) & 7;
  const unsigned short* gA2[2];
  const unsigned short* gB2[4];
#pragma unroll
  for (int j = 0; j < 2; ++j) {
    int r = (drow & 31) + (drow >> 5) * 64 + j * 32;  // phase-aligned slab rows
    int rc = r < mcnt ? r : (mcnt - 1);
    gA2[j] = H + (size_t)(hbase + start + rc) * F_DIM + g * 8;
  }
#pragma unroll
  for (int j = 0; j < 4; ++j) {
    int r = drow + j * 64;
    gB2[j] = w2t + (size_t)(e * D_DIM + n0 + r) * F_DIM + g * 8;
  }
  int arowbase = ((wv * 8) & 31) + ((wv * 8) >> 5) * 64;  // wave-uniform
  int ldstB = wv * 512;

  int kc16 = lane >> 4, r16 = lane & 15;
  int m_off = (wv & 1) * 64, n_off = (wv >> 1) * 64;

  f32x4 acc[4][4];
#pragma unroll
  for (int i = 0; i < 4; ++i)
#pragma unroll
    for (int j = 0; j < 4; ++j) acc[i][j] = (f32x4){0.f, 0.f, 0.f, 0.f};
  bf16x8 bfr[4][2];

  auto issueA = [&](int t, int j) {
    int kt = t < NK2 ? t : NK2 - 1;
    async_cp16(gA2[j] + kt * 64,
               smem + (t & 1) * 24576 + (arowbase + j * 32) * 64);
  };
  auto issueB = [&](int t, int j) {
    int kt = t < NK2 ? t : NK2 - 1;
    async_cp16(gB2[j] + kt * 64,
               smem + (t & 1) * 24576 + 8192 + ldstB + j * 4096);
  };

  auto phase = [&](int t, int q) {
    const unsigned short* Ab = smem + (t & 1) * 24576;
    const unsigned short* Bb = Ab + 8192;
    if (q == 0) {
#pragma unroll
      for (int j = 0; j < 4; ++j) {
        int rb = n_off + j * 16 + r16;
#pragma unroll
        for (int h = 0; h < 2; ++h)
          bfr[j][h] = *(const bf16x8*)(Bb + rb * 64 + ((h * 4 + kc16 + rb) & 7) * 8);
      }
    }
    bf16x8 af[2][2];
#pragma unroll
    for (int m2 = 0; m2 < 2; ++m2) {
      int ra = m_off + (2 * q + m2) * 16 + r16;
#pragma unroll
      for (int h = 0; h < 2; ++h)
        af[m2][h] = *(const bf16x8*)(Ab + ra * 64 + ((h * 4 + kc16 + ra) & 7) * 8);
    }
    if (q == 0) { issueB(t + 1, 3); issueA(t + 1, 1); }
    else        { issueB(t + 2, 0); issueB(t + 2, 1); issueB(t + 2, 2); issueA(t + 2, 0); }
    __builtin_amdgcn_s_setprio(1);
#pragma unroll
    for (int h = 0; h < 2; ++h)
#pragma unroll
      for (int m2 = 0; m2 < 2; ++m2)
#pragma unroll
        for (int j = 0; j < 4; ++j)
          acc[2 * q + m2][j] = __builtin_amdgcn_mfma_f32_16x16x32_bf16(
              af[m2][h], bfr[j][h], acc[2 * q + m2][j], 0, 0, 0);
    __builtin_amdgcn_s_setprio(0);
    if (q == 1) WAIT_VM4;
    WAIT_LGKM0;
    RAW_BARRIER;
  };

  // prologue: T0 all 6, T1's first 4; vmcnt(4) -> T0 landed.
  issueB(0, 0); issueB(0, 1); issueB(0, 2); issueB(0, 3);
  issueA(0, 0); issueA(0, 1);
  issueB(1, 0); issueB(1, 1); issueB(1, 2);
  issueA(1, 0);
  WAIT_VM4;
  RAW_BARRIER;

  for (int t = 0; t < NK2; ++t) { phase(t, 0); phase(t, 1); }
  WAIT_VM0;        // drain stray DMAs before epilogue/endpgm (LDS safety)

  int col = lane & 15, rbase = (lane >> 4) * 4;
  float bias[4];
#pragma unroll
  for (int j = 0; j < 4; ++j) bias[j] = b2[e * D_DIM + n0 + n_off + j * 16 + col];
#pragma unroll
  for (int i = 0; i < 4; ++i) {
#pragma unroll
    for (int rg = 0; rg < 4; ++rg) {
      int r = m_off + i * 16 + rbase + rg;
      if (r < mcnt) {
        int a = assign[e * T_TOK + start + r];
        float wt = topk_w[a];
        float* orow = out + (size_t)(a >> 1) * D_DIM + n0 + n_off + col;
#pragma unroll
        for (int j = 0; j < 4; ++j) {
          float v = acc[i][j][rg] + bias[j];
          atomicAdd(orow + j * 16, wt * v);  // 2 contenders/address
        }
      }
    }
  }
}

// ---------------- launcher ----------------

extern "C" void kernel_launch(void* const* d_in, const int* in_sizes, int n_in,
                              void* d_out, int out_size, void* d_ws, size_t ws_size,
                              hipStream_t stream) {
  const float* x      = (const float*)d_in[0];
  const float* gate_w = (const float*)d_in[1];
  const float* w1     = (const float*)d_in[2];
  const float* b1     = (const float*)d_in[3];
  const float* w2     = (const float*)d_in[4];
  const float* b2     = (const float*)d_in[5];
  float* out = (float*)d_out;

  char* ws = (char*)d_ws;
  size_t off = 0;
  auto alloc = [&](size_t bytes) {
    char* p = ws + off;
    off = (off + bytes + 255) & ~(size_t)255;
    return p;
  };
  unsigned short* xb   = (unsigned short*)alloc((size_t)T_TOK * D_DIM * 2);
  unsigned short* w1t  = (unsigned short*)alloc((size_t)E_NUM * D_DIM * F_DIM * 2);
  unsigned short* w2t  = (unsigned short*)alloc((size_t)E_NUM * D_DIM * F_DIM * 2);
  unsigned short* Hbuf = (unsigned short*)alloc((size_t)2 * T_TOK * F_DIM * 2);
  float* topk_w = (float*)alloc((size_t)2 * T_TOK * 4);
  int* topk_e   = (int*)alloc((size_t)2 * T_TOK * 4);
  int* assign   = (int*)alloc((size_t)E_NUM * T_TOK * 4);
  int* cnt      = (int*)alloc(64);
  int* ndesc    = (int*)alloc(64);
  int4* desc    = (int4*)alloc((size_t)MAX_TILES * 16);
  int4* desc2   = (int4*)alloc((size_t)MAX_TILES2 * 16);

  hipFuncSetAttribute(reinterpret_cast<const void*>(gemm1_kernel),
                      hipFuncAttributeMaxDynamicSharedMemorySize, 131072);
  hipFuncSetAttribute(reinterpret_cast<const void*>(gemm2_kernel),
                      hipFuncAttributeMaxDynamicSharedMemorySize, 98304);

  hipMemsetAsync(cnt, 0, 64, stream);
  hipMemsetAsync(out, 0, (size_t)out_size * 4, stream);

  transpose_cast_kernel<<<dim3(F_DIM / 64, D_DIM / 64, E_NUM), 256, 0, stream>>>(
      w1, w1t, D_DIM, F_DIM);  // [D][F] -> [F][D]
  transpose_cast_kernel<<<dim3(D_DIM / 64, F_DIM / 64, E_NUM), 256, 0, stream>>>(
      w2, w2t, F_DIM, D_DIM);  // [F][D] -> [D][F]
  gate_kernel<<<T_TOK / 4, 256, 0, stream>>>(x, gate_w, topk_w, topk_e, xb);
  scatter_kernel<<<2 * T_TOK / 256, 256, 0, stream>>>(topk_e, cnt, assign);
  tiles_kernel<<<1, 64, 0, stream>>>(cnt, ndesc, desc, desc2);
  gemm1_kernel<<<dim3(NX1, MAX_TILES), 512, 131072, stream>>>(
      xb, w1t, b1, assign, ndesc, desc, Hbuf);
  gemm2_kernel<<<dim3(NX2, MAX_TILES2), 512, 98304, stream>>>(
      Hbuf, w2t, b2, assign, topk_w, ndesc, desc2, out);
}